// Round 3
// baseline (1792.393 us; speedup 1.0000x reference)
//
#include <hip/hip_runtime.h>

// LIF two-layer SNN, bit-exact emulation of a float32 numpy/OpenBLAS reference.
// Binary spikes -> sgemm dot = ascending-k sequential f32 sum of active weight
// rows, blocked by OpenBLAS kc. This round: SkylakeX params (kc=320), the
// path OpenBLAS uses on AVX-512 Zen4/Zen5 hosts. Block partials combined in
// ascending block order. LIF update = separate f32 mul then add.
// All f32 ops via __fadd_rn/__fmul_rn to defeat -ffp-contract=fast.

#define T_STEPS 128
#define BATCH   512
#define NLAB    512
#define HID     1024
#define SEM     1024
// kc = 320 -> wave-aligned boundaries at waves 5, 10, 15 (320/640/960)
#define KCW     5

// 32x32 tiled transpose, block = (32,8). R,C multiples of 32. Exact copies.
__global__ __launch_bounds__(256) void transpose32(const float* __restrict__ in,
                                                   float* __restrict__ out,
                                                   int R, int C) {
    __shared__ float tile[32][33];
    const int c0 = blockIdx.x * 32, r0 = blockIdx.y * 32;
    const int x = threadIdx.x, y0 = threadIdx.y;
#pragma unroll
    for (int i = 0; i < 32; i += 8)
        tile[y0 + i][x] = in[(size_t)(r0 + y0 + i) * C + (c0 + x)];
    __syncthreads();
#pragma unroll
    for (int i = 0; i < 32; i += 8)
        out[(size_t)(c0 + y0 + i) * R + (r0 + x)] = tile[x][y0 + i];
}

__global__ __launch_bounds__(1024, 2)
void snn_kernel(const float* __restrict__ spikes,   // (T, B, NLAB)
                const float* __restrict__ w1t,      // (NLAB, HID) = W1^T
                const float* __restrict__ w2t,      // (HID, SEM)  = W2^T
                float* __restrict__ out) {          // (B*HID) ++ (B*SEM)
    __shared__ int wc1[8];            // per-wave active counts, input spikes
    __shared__ int wc2[16];           // per-wave spike counts, layer 1
    __shared__ int list1[NLAB];       // ascending active input indices
    __shared__ int list2[HID];        // ascending spiking hidden indices

    const int b    = blockIdx.x;
    const int tid  = threadIdx.x;
    const int w    = tid >> 6;
    const int lane = tid & 63;

    float v1 = 0.0f, v2 = 0.0f;
    int c1 = 0, c2 = 0;
    const float* sp_b = spikes + (size_t)b * NLAB;

    for (int t = 0; t < T_STEPS; ++t) {
        // ---- stage 1a: per-wave count of active inputs ----
        bool act = false;
        int pre1 = 0;
        if (tid < NLAB) {                       // waves 0..7, wave-uniform branch
            act = (sp_b[(size_t)t * (BATCH * NLAB) + tid] != 0.0f);
            const unsigned long long m = __ballot(act);
            pre1 = __popcll(m & ((1ull << lane) - 1ull));
            if (lane == 0) wc1[w] = __popcll(m);
        }
        __syncthreads();                        // wc1 ready; prev stage-3 done

        // ---- stage 1b: deterministic ascending compaction ----
        if (act) {
            int base = 0;
            for (int i = 0; i < w; ++i) base += wc1[i];
            list1[base + pre1] = tid;
        }
        __syncthreads();                        // list1 ready

        // ---- stage 2: layer 1, h = tid. kc blocks [0,320),[320,512) ----
        bool spk;
        int pre2 = 0;
        {
            int nA = 0, n1 = 0;
            {
                int s = 0;
#pragma unroll
                for (int i = 0; i < 8; ++i) { s += wc1[i]; if (i == KCW - 1) nA = s; }
                n1 = s;
            }
            const float* col = w1t + tid;       // column h, stride HID
            float s1 = 0.0f, s2 = 0.0f;
            for (int k = 0; k < nA; ++k)
                s1 = __fadd_rn(s1, col[(size_t)list1[k] * HID]);
            for (int k = nA; k < n1; ++k)
                s2 = __fadd_rn(s2, col[(size_t)list1[k] * HID]);
            const float x1 = __fadd_rn(s1, s2);

            v1 = __fadd_rn(__fmul_rn(0.95f, v1), x1);
            spk = (v1 > 1.0f);
            if (spk) { c1++; v1 = 0.0f; }

            const unsigned long long m = __ballot(spk);
            pre2 = __popcll(m & ((1ull << lane) - 1ull));
            if (lane == 0) wc2[w] = __popcll(m);
        }
        __syncthreads();                        // wc2 ready

        if (spk) {
            int base = 0;
            for (int i = 0; i < w; ++i) base += wc2[i];
            list2[base + pre2] = tid;
        }
        __syncthreads();                        // list2 ready

        // ---- stage 3: layer 2, s = tid. kc blocks 320/320/320/64 ----
        {
            int nA = 0, nB = 0, nC = 0, n2 = 0;
            {
                int s = 0;
#pragma unroll
                for (int i = 0; i < 16; ++i) {
                    s += wc2[i];
                    if (i == KCW - 1)     nA = s;   // < 320
                    if (i == 2 * KCW - 1) nB = s;   // < 640
                    if (i == 3 * KCW - 1) nC = s;   // < 960
                }
                n2 = s;
            }
            const float* col = w2t + tid;       // column s, stride SEM
            float t1 = 0.0f, t2 = 0.0f, t3 = 0.0f, t4 = 0.0f;
            for (int k = 0; k < nA; ++k)
                t1 = __fadd_rn(t1, col[(size_t)list2[k] * SEM]);
            for (int k = nA; k < nB; ++k)
                t2 = __fadd_rn(t2, col[(size_t)list2[k] * SEM]);
            for (int k = nB; k < nC; ++k)
                t3 = __fadd_rn(t3, col[(size_t)list2[k] * SEM]);
            for (int k = nC; k < n2; ++k)
                t4 = __fadd_rn(t4, col[(size_t)list2[k] * SEM]);
            const float x2 = __fadd_rn(__fadd_rn(__fadd_rn(t1, t2), t3), t4);

            v2 = __fadd_rn(__fmul_rn(0.95f, v2), x2);
            if (v2 > 1.0f) { c2++; v2 = 0.0f; }
        }
        __syncthreads();                        // list2/wc2 free for next iter
    }

    out[(size_t)b * HID + tid]                       = (float)c1 * (1.0f / 128.0f);
    out[(size_t)BATCH * HID + (size_t)b * SEM + tid] = (float)c2 * (1.0f / 128.0f);
}

extern "C" void kernel_launch(void* const* d_in, const int* in_sizes, int n_in,
                              void* d_out, int out_size, void* d_ws, size_t ws_size,
                              hipStream_t stream) {
    const float* spikes = (const float*)d_in[0];  // (128, 512, 512)
    const float* W1     = (const float*)d_in[1];  // (1024, 512)
    const float* W2     = (const float*)d_in[2];  // (1024, 1024)
    float* out = (float*)d_out;

    float* w1t = (float*)d_ws;                    // (512, 1024)
    float* w2t = w1t + (size_t)NLAB * HID;        // (1024, 1024) — 6 MB total

    dim3 tb(32, 8);
    transpose32<<<dim3(NLAB / 32, HID / 32), tb, 0, stream>>>(W1, w1t, HID, NLAB);
    transpose32<<<dim3(HID / 32, SEM / 32),  tb, 0, stream>>>(W2, w2t, SEM, HID);

    snn_kernel<<<BATCH, 1024, 0, stream>>>(spikes, w1t, w2t, out);
}

// Round 4
// 1771.158 us; speedup vs baseline: 1.0120x; 1.0120x over previous
//
#include <hip/hip_runtime.h>

// LIF two-layer SNN, bit-exact emulation of a float32 numpy/OpenBLAS reference
// (SkylakeX sgemm: kc=320 K-blocking, sequential ascending-k f32 chains per
// block, block partials combined in order; LIF = separate f32 mul then add).
// Round 4: uniform scalar addressing (readfirstlane) + 8-deep load pipeline
// in the gather loops. Chain ADD ORDER IS UNCHANGED -> still bit-exact.

#define T_STEPS 128
#define BATCH   512
#define NLAB    512
#define HID     1024
#define SEM     1024
// kc = 320 -> wave-aligned boundaries at waves 5, 10, 15 (320/640/960)
#define KCW     5

// 32x32 tiled transpose, block = (32,8). R,C multiples of 32. Exact copies.
__global__ __launch_bounds__(256) void transpose32(const float* __restrict__ in,
                                                   float* __restrict__ out,
                                                   int R, int C) {
    __shared__ float tile[32][33];
    const int c0 = blockIdx.x * 32, r0 = blockIdx.y * 32;
    const int x = threadIdx.x, y0 = threadIdx.y;
#pragma unroll
    for (int i = 0; i < 32; i += 8)
        tile[y0 + i][x] = in[(size_t)(r0 + y0 + i) * C + (c0 + x)];
    __syncthreads();
#pragma unroll
    for (int i = 0; i < 32; i += 8)
        out[(size_t)(c0 + y0 + i) * R + (r0 + x)] = tile[x][y0 + i];
}

// Sequential ascending-k f32 add chain over list[lo..hi) of weight rows
// (row stride 1024 floats), 8-deep load pipeline, wave-uniform scalar
// addressing. The fadd order is strictly k-ascending -> bit-exact.
__device__ __forceinline__ float gather_chain(const int* __restrict__ list,
                                              int lo, int hi,
                                              const float* __restrict__ base,
                                              int tid, float s) {
    int k = lo;
    for (; k + 8 <= hi; k += 8) {
        float w[8];
#pragma unroll
        for (int j = 0; j < 8; ++j) {
            const int row = __builtin_amdgcn_readfirstlane(list[k + j]);
            w[j] = base[((size_t)row << 10) + tid];
        }
#pragma unroll
        for (int j = 0; j < 8; ++j)
            s = __fadd_rn(s, w[j]);
    }
    for (; k < hi; ++k) {
        const int row = __builtin_amdgcn_readfirstlane(list[k]);
        s = __fadd_rn(s, base[((size_t)row << 10) + tid]);
    }
    return s;
}

__global__ __launch_bounds__(1024, 8)
void snn_kernel(const float* __restrict__ spikes,   // (T, B, NLAB)
                const float* __restrict__ w1t,      // (NLAB, HID) = W1^T
                const float* __restrict__ w2t,      // (HID, SEM)  = W2^T
                float* __restrict__ out) {          // (B*HID) ++ (B*SEM)
    __shared__ int wc1[8];            // per-wave active counts, input spikes
    __shared__ int wc2[16];           // per-wave spike counts, layer 1
    __shared__ __align__(16) int list1[NLAB];   // ascending active inputs
    __shared__ __align__(16) int list2[HID];    // ascending spiking hidden

    const int b    = blockIdx.x;
    const int tid  = threadIdx.x;
    const int w    = tid >> 6;
    const int lane = tid & 63;

    float v1 = 0.0f, v2 = 0.0f;
    int c1 = 0, c2 = 0;
    const float* sp_b = spikes + (size_t)b * NLAB;

    for (int t = 0; t < T_STEPS; ++t) {
        // ---- stage 1a: per-wave count of active inputs ----
        bool act = false;
        int pre1 = 0;
        if (tid < NLAB) {                       // waves 0..7, wave-uniform branch
            act = (sp_b[(size_t)t * (BATCH * NLAB) + tid] != 0.0f);
            const unsigned long long m = __ballot(act);
            pre1 = __popcll(m & ((1ull << lane) - 1ull));
            if (lane == 0) wc1[w] = __popcll(m);
        }
        __syncthreads();                        // wc1 ready; prev stage-3 done

        // ---- stage 1b: deterministic ascending compaction ----
        if (act) {
            int base = 0;
            for (int i = 0; i < w; ++i) base += wc1[i];
            list1[base + pre1] = tid;
        }
        __syncthreads();                        // list1 ready

        // ---- stage 2: layer 1, h = tid. kc blocks [0,320),[320,512) ----
        bool spk;
        int pre2 = 0;
        {
            int nA = 0, n1 = 0;
            {
                int s = 0;
#pragma unroll
                for (int i = 0; i < 8; ++i) { s += wc1[i]; if (i == KCW - 1) nA = s; }
                n1 = s;
            }
            const float x1 = __fadd_rn(gather_chain(list1, 0,  nA, w1t, tid, 0.0f),
                                       gather_chain(list1, nA, n1, w1t, tid, 0.0f));

            v1 = __fadd_rn(__fmul_rn(0.95f, v1), x1);
            spk = (v1 > 1.0f);
            if (spk) { c1++; v1 = 0.0f; }

            const unsigned long long m = __ballot(spk);
            pre2 = __popcll(m & ((1ull << lane) - 1ull));
            if (lane == 0) wc2[w] = __popcll(m);
        }
        __syncthreads();                        // wc2 ready

        if (spk) {
            int base = 0;
            for (int i = 0; i < w; ++i) base += wc2[i];
            list2[base + pre2] = tid;
        }
        __syncthreads();                        // list2 ready

        // ---- stage 3: layer 2, s = tid. kc blocks 320/320/320/64 ----
        {
            int nA = 0, nB = 0, nC = 0, n2 = 0;
            {
                int s = 0;
#pragma unroll
                for (int i = 0; i < 16; ++i) {
                    s += wc2[i];
                    if (i == KCW - 1)     nA = s;   // < 320
                    if (i == 2 * KCW - 1) nB = s;   // < 640
                    if (i == 3 * KCW - 1) nC = s;   // < 960
                }
                n2 = s;
            }
            const float t1 = gather_chain(list2, 0,  nA, w2t, tid, 0.0f);
            const float t2 = gather_chain(list2, nA, nB, w2t, tid, 0.0f);
            const float t3 = gather_chain(list2, nB, nC, w2t, tid, 0.0f);
            const float t4 = gather_chain(list2, nC, n2, w2t, tid, 0.0f);
            const float x2 = __fadd_rn(__fadd_rn(__fadd_rn(t1, t2), t3), t4);

            v2 = __fadd_rn(__fmul_rn(0.95f, v2), x2);
            if (v2 > 1.0f) { c2++; v2 = 0.0f; }
        }
        __syncthreads();                        // list2/wc2 free for next iter
    }

    out[(size_t)b * HID + tid]                       = (float)c1 * (1.0f / 128.0f);
    out[(size_t)BATCH * HID + (size_t)b * SEM + tid] = (float)c2 * (1.0f / 128.0f);
}

extern "C" void kernel_launch(void* const* d_in, const int* in_sizes, int n_in,
                              void* d_out, int out_size, void* d_ws, size_t ws_size,
                              hipStream_t stream) {
    const float* spikes = (const float*)d_in[0];  // (128, 512, 512)
    const float* W1     = (const float*)d_in[1];  // (1024, 512)
    const float* W2     = (const float*)d_in[2];  // (1024, 1024)
    float* out = (float*)d_out;

    float* w1t = (float*)d_ws;                    // (512, 1024)
    float* w2t = w1t + (size_t)NLAB * HID;        // (1024, 1024) — 6 MB total

    dim3 tb(32, 8);
    transpose32<<<dim3(NLAB / 32, HID / 32), tb, 0, stream>>>(W1, w1t, HID, NLAB);
    transpose32<<<dim3(HID / 32, SEM / 32),  tb, 0, stream>>>(W2, w2t, SEM, HID);

    snn_kernel<<<BATCH, 1024, 0, stream>>>(spikes, w1t, w2t, out);
}